// Round 1
// 2324.776 us; speedup vs baseline: 1.1549x; 1.1549x over previous
//
#include <hip/hip_runtime.h>
#include <stdint.h>

typedef uint16_t u16;
typedef uint32_t u32;
typedef __attribute__((ext_vector_type(8))) short short8;
typedef __attribute__((ext_vector_type(4))) float f32x4;

// ---------- constants ----------
constexpr int B_  = 64;
constexpr int C_  = 2048;
constexpr int CI_ = 1024;
constexpr int N_  = 512;     // H*W
constexpr int CHB = 32;      // batches per chunk (2 chunks)

// ---------- bf16 helpers ----------
__device__ __forceinline__ float bf2f(u16 h){
  union{u32 u; float f;} v; v.u = ((u32)h) << 16; return v.f;
}
__device__ __forceinline__ u16 f2bf(float x){
  union{float f; u32 u;} v; v.f = x;
  u32 u = v.u;
  u32 r = u + 0x7fffu + ((u >> 16) & 1u);
  return (u16)(r >> 16);
}
__device__ __forceinline__ u32 split2(float v){
  u16 hi = f2bf(v);
  u16 lo = f2bf(v - bf2f(hi));
  return (u32)hi | ((u32)lo << 16);
}

// ---------- async global->LDS (16B per lane) ----------
__device__ __forceinline__ void gld_lds16(const void* gsrc, void* ldst){
  __builtin_amdgcn_global_load_lds(
      (__attribute__((address_space(1))) void*)(const_cast<void*>(gsrc)),
      (__attribute__((address_space(3))) void*)(ldst), 16, 0, 0);
}

// =====================================================================
// Pipelined NT GEMM: Out[m][n] = sum_k A[m][k]*B[n][k]  (+bias)
// 256x256 tile, BK=32, 512 threads (8 waves 2x4), per-wave 128x64.
// 4 LDS slots (128 KiB), prefetch distance 3, counted vmcnt(12) --
// loads stay in flight across raw s_barriers (T3/T4). LDS chunk XOR
// swizzle applied on BOTH the staging global source and the ds_read
// (T2, rule 21: global_load_lds dest must stay linear). setprio (T5)
// around the MFMA cluster.
// Race-safety: slot (t+3)&3 == slot (t-1)&3 was fully consumed before
// the end-of-iter barrier of t-1; staging at iter t is after it.
// vmcnt invariant: pool at iter t <= tiles {t..t+3} (16 loads);
// vmcnt(12) forces tile t landed. Tail drains 8->4->0.
// =====================================================================
template<int BIAS_MODE, int OUT_MODE, bool BSPLIT>
__global__ __launch_bounds__(512, 2)
void gemm_nt_p4(const u16* __restrict__ A, long aBatch, int lda,
                const u16* __restrict__ Bm, long bBatch, int ldb,
                void* __restrict__ Out, long oBatch, int ldo,
                const float* __restrict__ bias, int K)
{
  constexpr int BK   = 32;
  constexpr int SLOT = 512 * BK;            // u16 per slot (A 256x32 + B 256x32)
  __shared__ __align__(16) u16 sm[4 * SLOT];  // 128 KiB

  const int bz = blockIdx.z;
  const int tm = blockIdx.x * 256;
  const int tn = blockIdx.y * 256;
  const u16* Ab = A  + (long)bz * aBatch;
  const u16* Bb = Bm + (long)bz * bBatch;

  const int tid  = threadIdx.x;
  const int wave = tid >> 6;
  const int lane = tid & 63;
  const int wr   = wave >> 2;               // 0..1  (M half)
  const int wc   = wave & 3;                // 0..3  (N quarter)
  const int lrow = lane & 15;
  const int quad = lane >> 4;

  // ---- staging: thread -> (row, chunk) of the linear LDS fill ----
  // LDS pos chunk (row,qp) receives global chunk (qp ^ swz(row)),
  // swz(row) = (row>>1)&3. Readers apply the same XOR -> transparent.
  const int srow = tid >> 2;                                   // 0..127
  const int scol = ((tid & 3) ^ ((srow >> 1) & 3)) << 3;       // u16 offset in row
  const u16* pa = Ab + (long)(tm + srow) * lda + scol;
  const u16* pb = Bb + (long)(tn + srow) * ldb + scol;
  const long a128 = (long)128 * lda;
  const long b128 = (long)128 * ldb;

  const int NT = K / BK;

  f32x4 acc[8][4];
#pragma unroll
  for (int i = 0; i < 8; ++i)
#pragma unroll
    for (int j = 0; j < 4; ++j) acc[i][j] = f32x4{0.f, 0.f, 0.f, 0.f};

#define STAGE(kt) do{ \
    u16* sl = &sm[((kt) & 3) * SLOT]; \
    const u16* ga = pa + (long)(kt) * BK; \
    const u16* gb = pb + (long)(kt) * BK; \
    gld_lds16(ga,        sl +         wave * 512); \
    gld_lds16(ga + a128, sl + 4096 +  wave * 512); \
    gld_lds16(gb,        sl + 8192 +  wave * 512); \
    gld_lds16(gb + b128, sl + 12288 + wave * 512); \
  }while(0)

#define COMPUTE(tt) do{ \
    const u16* Asl = &sm[((tt) & 3) * SLOT]; \
    const u16* Bsl = Asl + 8192; \
    short8 af[8], bfr[4], bsw[4]; \
    _Pragma("unroll") \
    for (int i = 0; i < 8; ++i){ \
      const int r8 = i * 16 + lrow; \
      af[i] = *(const short8*)&Asl[(wr * 128 + r8) * BK + ((quad ^ ((r8 >> 1) & 3)) << 3)]; \
    } \
    _Pragma("unroll") \
    for (int j = 0; j < 4; ++j){ \
      const int n8 = j * 16 + lrow; \
      bfr[j] = *(const short8*)&Bsl[(wc * 64 + n8) * BK + ((quad ^ ((n8 >> 1) & 3)) << 3)]; \
      if (BSPLIT) bsw[j] = __builtin_shufflevector(bfr[j], bfr[j], 1, 0, 3, 2, 5, 4, 7, 6); \
    } \
    __builtin_amdgcn_s_setprio(1); \
    _Pragma("unroll") \
    for (int i = 0; i < 8; ++i) \
      _Pragma("unroll") \
      for (int j = 0; j < 4; ++j){ \
        acc[i][j] = __builtin_amdgcn_mfma_f32_16x16x32_bf16(af[i], bfr[j], acc[i][j], 0, 0, 0); \
        if (BSPLIT) \
          acc[i][j] = __builtin_amdgcn_mfma_f32_16x16x32_bf16(af[i], bsw[j], acc[i][j], 0, 0, 0); \
      } \
    __builtin_amdgcn_s_setprio(0); \
  }while(0)

#define KITER(tt, VM) do{ \
    asm volatile("s_waitcnt vmcnt(" VM ")" ::: "memory"); \
    __builtin_amdgcn_s_barrier(); \
    asm volatile("" ::: "memory"); \
    COMPUTE(tt); \
    asm volatile("" ::: "memory"); \
    __builtin_amdgcn_s_barrier(); \
    asm volatile("" ::: "memory"); \
  }while(0)

  STAGE(0); STAGE(1); STAGE(2);

  int t = 0;
  for (; t < NT - 3; ++t){
    STAGE(t + 3);
    KITER(t, "12");
  }
  KITER(t, "8");  ++t;   // tail: drain 8 -> 4 -> 0
  KITER(t, "4");  ++t;
  KITER(t, "0");

#undef KITER
#undef COMPUTE
#undef STAGE

  // epilogue: D[row][col], col=lane&15, row=quad*4+r (verified m89/m91)
  const long obase = (long)bz * oBatch;
#pragma unroll
  for (int i = 0; i < 8; ++i){
    const int rbase = tm + wr * 128 + i * 16 + quad * 4;
#pragma unroll
    for (int j = 0; j < 4; ++j){
      const int col = tn + wc * 64 + j * 16 + lrow;
      float cb = 0.f;
      if (BIAS_MODE == 2) cb = bias[col];
#pragma unroll
      for (int r = 0; r < 4; ++r){
        const int row = rbase + r;
        float v = acc[i][j][r];
        if (BIAS_MODE == 1) v += bias[row];
        if (BIAS_MODE == 2) v += cb;
        if (OUT_MODE == 1){
          ((float*)Out)[obase + (long)row * ldo + col] = v;
        } else if (OUT_MODE == 0){
          ((u16*)Out)[obase + (long)row * ldo + col] = f2bf(v);
        } else {
          *(u32*)((u16*)Out + obase + (long)row * ldo + col * 2) = split2(v);
        }
      }
    }
  }
}

// =====================================================================
// Old 128x128 NT GEMM (kept for f = th.ph: 512x512 -> 512 blocks keeps
// all CUs busy; at 256^2 only 128 blocks would run).
// =====================================================================
template<int BIAS_MODE, int OUT_MODE, bool BSPLIT>
__global__ __launch_bounds__(256)
void gemm_nt(const u16* __restrict__ A, long aBatch, int lda,
             const u16* __restrict__ Bm, long bBatch, int ldb,
             void* __restrict__ Out, long oBatch, int ldo,
             const float* __restrict__ bias, int K)
{
  constexpr int TM = 128, TN = 128, BK = 32;
  const int bz = blockIdx.z;
  const int tm = blockIdx.x * TM;
  const int tn = blockIdx.y * TN;
  const u16* Ab = A  + (long)bz * aBatch;
  const u16* Bb = Bm + (long)bz * bBatch;

  __shared__ __align__(16) u16 As[TM * BK];
  __shared__ __align__(16) u16 Bs[TN * BK];

  const int tid  = threadIdx.x;
  const int wave = tid >> 6;
  const int lane = tid & 63;
  const int wm   = (wave & 1) << 6;
  const int wn   = (wave >> 1) << 6;
  const int lrow = lane & 15;
  const int quad = lane >> 4;

  f32x4 acc[4][4];
#pragma unroll
  for (int i = 0; i < 4; ++i)
#pragma unroll
    for (int j = 0; j < 4; ++j)
      acc[i][j] = f32x4{0.f, 0.f, 0.f, 0.f};

  for (int k0 = 0; k0 < K; k0 += BK){
#pragma unroll
    for (int it = 0; it < 2; ++it){
      const int c   = it * 256 + wave * 64 + lane;
      const int row = c >> 2;
      const int col = (c & 3) << 3;
      const u16* srcA = Ab + (long)(tm + row) * lda + k0 + col;
      const u16* srcB = Bb + (long)(tn + row) * ldb + k0 + col;
      gld_lds16(srcA, &As[(it * 256 + wave * 64) * 8]);
      gld_lds16(srcB, &Bs[(it * 256 + wave * 64) * 8]);
    }
    __syncthreads();

    short8 af[4], bfr[4];
#pragma unroll
    for (int t = 0; t < 4; ++t){
      af[t]  = *(const short8*)&As[(wm + t * 16 + lrow) * BK + quad * 8];
      bfr[t] = *(const short8*)&Bs[(wn + t * 16 + lrow) * BK + quad * 8];
    }
#pragma unroll
    for (int i = 0; i < 4; ++i)
#pragma unroll
      for (int j = 0; j < 4; ++j){
        acc[i][j] = __builtin_amdgcn_mfma_f32_16x16x32_bf16(af[i], bfr[j], acc[i][j], 0, 0, 0);
        if (BSPLIT){
          short8 bs = __builtin_shufflevector(bfr[j], bfr[j], 1, 0, 3, 2, 5, 4, 7, 6);
          acc[i][j] = __builtin_amdgcn_mfma_f32_16x16x32_bf16(af[i], bs, acc[i][j], 0, 0, 0);
        }
      }
    __syncthreads();
  }

  const long obase = (long)bz * oBatch;
#pragma unroll
  for (int i = 0; i < 4; ++i){
    const int rbase = tm + wm + i * 16 + quad * 4;
#pragma unroll
    for (int j = 0; j < 4; ++j){
      const int col = tn + wn + j * 16 + lrow;
      float cb = 0.f;
      if (BIAS_MODE == 2) cb = bias[col];
#pragma unroll
      for (int r = 0; r < 4; ++r){
        const int row = rbase + r;
        float v = acc[i][j][r];
        if (BIAS_MODE == 1) v += bias[row];
        if (BIAS_MODE == 2) v += cb;
        if (OUT_MODE == 1){
          ((float*)Out)[obase + (long)row * ldo + col] = v;
        } else if (OUT_MODE == 0){
          ((u16*)Out)[obase + (long)row * ldo + col] = f2bf(v);
        } else {
          *(u32*)((u16*)Out + obase + (long)row * ldo + col * 2) = split2(v);
        }
      }
    }
  }
}

// =====================================================================
// Transpose+split chunk: x [CHB,C,N] fp32 -> xT2 [CHB,N,2C] bf16 hi/lo
// =====================================================================
__global__ __launch_bounds__(1024)
void transpose_split_k(const float* __restrict__ x, u32* __restrict__ xT2)
{
  __shared__ float t[32][33];
  const int b  = blockIdx.z;
  const int n0 = blockIdx.x << 5;
  const int c0 = blockIdx.y << 5;
  const float* xb = x + (long)b * ((long)C_ * N_);
  u32* xo = xT2 + (long)b * ((long)N_ * C_);
  t[threadIdx.y][threadIdx.x] = xb[(long)(c0 + threadIdx.y) * N_ + n0 + threadIdx.x];
  __syncthreads();
  xo[(long)(n0 + threadIdx.y) * C_ + c0 + threadIdx.x] = split2(t[threadIdx.x][threadIdx.y]);
}

// =====================================================================
// Weight split: W fp32 [n] -> W2 u32 (bf16 hi|lo)
// =====================================================================
__global__ __launch_bounds__(256)
void wsplit_k(const float* __restrict__ W, u32* __restrict__ W2)
{
  const long i = ((long)blockIdx.x * 256 + threadIdx.x) * 4;
  const float4 v = *(const float4*)(W + i);
  uint4 o;
  o.x = split2(v.x); o.y = split2(v.y); o.z = split2(v.z); o.w = split2(v.w);
  *(uint4*)(W2 + i) = o;
}

// =====================================================================
// Plain fp32 -> bf16 pack (for Wo)
// =====================================================================
__global__ __launch_bounds__(256)
void pack_bf16_k(const float* __restrict__ W, u16* __restrict__ Wb)
{
  const long i = ((long)blockIdx.x * 256 + threadIdx.x) * 8;
  const float4 a = *(const float4*)(W + i);
  const float4 b = *(const float4*)(W + i + 4);
  uint4 o;
  o.x = (u32)f2bf(a.x) | ((u32)f2bf(a.y) << 16);
  o.y = (u32)f2bf(a.z) | ((u32)f2bf(a.w) << 16);
  o.z = (u32)f2bf(b.x) | ((u32)f2bf(b.y) << 16);
  o.w = (u32)f2bf(b.z) | ((u32)f2bf(b.w) << 16);
  *(uint4*)(Wb + i) = o;
}

// =====================================================================
// Row softmax over f [rows, 512] fp32; writes bf16 attn IN PLACE at row
// start (row stride stays 512 floats = 1024 u16).
// =====================================================================
__global__ __launch_bounds__(256)
void softmax_k(float* __restrict__ f)
{
  const long row = blockIdx.x;
  float* fr = f + (row << 9);
  const int tid = threadIdx.x;
  const float v0 = fr[tid];
  const float v1 = fr[tid + 256];

  float m = fmaxf(v0, v1);
#pragma unroll
  for (int off = 32; off; off >>= 1) m = fmaxf(m, __shfl_xor(m, off, 64));
  __shared__ float red[8];
  const int wave = tid >> 6, lane = tid & 63;
  if (!lane) red[wave] = m;
  __syncthreads();
  m = fmaxf(fmaxf(red[0], red[1]), fmaxf(red[2], red[3]));

  const float e0 = __expf(v0 - m);
  const float e1 = __expf(v1 - m);
  float s = e0 + e1;
#pragma unroll
  for (int off = 32; off; off >>= 1) s += __shfl_xor(s, off, 64);
  if (!lane) red[4 + wave] = s;
  __syncthreads();
  const float rs = 1.f / (red[4] + red[5] + red[6] + red[7]);

  u16* ar = (u16*)fr;
  ar[tid]       = f2bf(e0 * rs);
  ar[tid + 256] = f2bf(e1 * rs);
}

// =====================================================================
// BN stats per channel over (b,n): mean | rstd  (wy bf16 [B,C,N])
// =====================================================================
__global__ __launch_bounds__(256)
void bn_stats_k(const u16* __restrict__ wy, float* __restrict__ stats)
{
  const int c = blockIdx.x;
  const int tid = threadIdx.x;
  float s = 0.f, q = 0.f;
  const u16* base = wy + (long)c * N_;
  for (int b = 0; b < B_; ++b){
    const u32 w = ((const u32*)(base + (long)b * ((long)C_ * N_)))[tid];
    const float a0 = bf2f((u16)(w & 0xffff));
    const float a1 = bf2f((u16)(w >> 16));
    s += a0 + a1;
    q += a0 * a0 + a1 * a1;
  }
#pragma unroll
  for (int off = 32; off; off >>= 1){ s += __shfl_xor(s, off, 64); q += __shfl_xor(q, off, 64); }
  __shared__ float rs_[4], rq_[4];
  const int wave = tid >> 6, lane = tid & 63;
  if (!lane){ rs_[wave] = s; rq_[wave] = q; }
  __syncthreads();
  if (tid == 0){
    const float S = rs_[0] + rs_[1] + rs_[2] + rs_[3];
    const float Q = rq_[0] + rq_[1] + rq_[2] + rq_[3];
    const float inv = 1.f / (float)(B_ * N_);
    const float mean = S * inv;
    const float var  = Q * inv - mean * mean;
    stats[c]      = mean;
    stats[C_ + c] = rsqrtf(var + 1e-5f);
  }
}

// =====================================================================
// BN apply + residual: out = (wy-mean)*rstd*gamma + beta + x  (fp32 out)
// =====================================================================
__global__ __launch_bounds__(256)
void bn_apply_k(const u16* __restrict__ wy, const float* __restrict__ x,
                const float* __restrict__ stats,
                const float* __restrict__ gamma, const float* __restrict__ beta,
                float* __restrict__ out)
{
  const long i = ((long)blockIdx.x * 256 + threadIdx.x) * 8;
  const int c = (int)((i >> 9) & (C_ - 1));
  const float a  = stats[C_ + c] * gamma[c];
  const float b0 = beta[c] - stats[c] * a;

  const uint4 wv = *(const uint4*)(wy + i);
  const float4 x0 = *(const float4*)(x + i);
  const float4 x1 = *(const float4*)(x + i + 4);
  float4 o0, o1;
  o0.x = bf2f((u16)(wv.x & 0xffff)) * a + b0 + x0.x;
  o0.y = bf2f((u16)(wv.x >> 16))    * a + b0 + x0.y;
  o0.z = bf2f((u16)(wv.y & 0xffff)) * a + b0 + x0.z;
  o0.w = bf2f((u16)(wv.y >> 16))    * a + b0 + x0.w;
  o1.x = bf2f((u16)(wv.z & 0xffff)) * a + b0 + x1.x;
  o1.y = bf2f((u16)(wv.z >> 16))    * a + b0 + x1.y;
  o1.z = bf2f((u16)(wv.w & 0xffff)) * a + b0 + x1.z;
  o1.w = bf2f((u16)(wv.w >> 16))    * a + b0 + x1.w;
  *(float4*)(out + i)     = o0;
  *(float4*)(out + i + 4) = o1;
}

// =====================================================================
extern "C" void kernel_launch(void* const* d_in, const int* in_sizes, int n_in,
                              void* d_out, int out_size, void* d_ws, size_t ws_size,
                              hipStream_t stream)
{
  (void)in_sizes; (void)n_in; (void)out_size; (void)ws_size;
  const float* x     = (const float*)d_in[0];
  const float* Wg    = (const float*)d_in[1];
  const float* bg    = (const float*)d_in[2];
  const float* Wt    = (const float*)d_in[3];
  const float* bt    = (const float*)d_in[4];
  const float* Wp    = (const float*)d_in[5];
  const float* bp    = (const float*)d_in[6];
  const float* Wo    = (const float*)d_in[7];
  const float* bo    = (const float*)d_in[8];
  const float* gamma = (const float*)d_in[9];
  const float* beta  = (const float*)d_in[10];
  float* out = (float*)d_out;

  // ---- scratch in d_out (fully rewritten by bn_apply at the end) ----
  char* ob = (char*)d_out;
  u16* xT2 = (u16*)ob;
  u16* th2 = (u16*)(ob + 134217728L);
  u16* ph2 = (u16*)(ob + 134217728L + 67108864L);

  // ---- d_ws layout (~252 MiB) ----
  char* ws = (char*)d_ws;
  u16*   wy  = (u16*)ws;                         // [B,C,N] bf16  128 MiB
  u16*   g   = (u16*)(ws + 134217728L);          // chunk [CHB,Ci,N] 32 MiB
  float* f   = (float*)(ws + 134217728L + 33554432L);          // chunk 32 MiB
  u16*   yT  = (u16*)(ws + 134217728L + 2*33554432L);          // chunk 32 MiB
  u32*   Wg2 = (u32*)(ws + 134217728L + 3*33554432L);          // 8 MiB
  u32*   Wt2 = Wg2 + 2097152L;                                  // 8 MiB
  u32*   Wp2 = Wt2 + 2097152L;                                  // 8 MiB
  u16*   Wob = (u16*)(Wp2 + 2097152L);                          // 4 MiB
  float* stats = (float*)(Wob + 2097152L);                      // 16 KiB

  // ---- weight conversions (once per launch) ----
  wsplit_k<<<dim3(2097152 / (256 * 4)), 256, 0, stream>>>(Wg, Wg2);
  wsplit_k<<<dim3(2097152 / (256 * 4)), 256, 0, stream>>>(Wt, Wt2);
  wsplit_k<<<dim3(2097152 / (256 * 4)), 256, 0, stream>>>(Wp, Wp2);
  pack_bf16_k<<<dim3(2097152 / (256 * 8)), 256, 0, stream>>>(Wo, Wob);

  const long xBatch   = (long)C_ * N_;      // fp32 elems per batch of x
  const long xt2B     = (long)N_ * 2 * C_;  // u16 per batch
  const long th2B     = (long)N_ * 2 * CI_;
  const long gB       = (long)CI_ * N_;
  const long fB       = (long)N_ * N_;      // fp32
  const long attnB    = (long)N_ * 1024;    // u16 (row stride 1024)
  const long yB       = (long)N_ * CI_;
  const long wyB      = (long)C_ * N_;

  for (int h = 0; h < 2; ++h){
    const float* xc = x + (long)h * CHB * xBatch;

    // 1) transpose + hi/lo split
    transpose_split_k<<<dim3(N_ / 32, C_ / 32, CHB), dim3(32, 32), 0, stream>>>(
        xc, (u32*)xT2);

    // 2) th2[n][2o] = xT2 . Wt2 (pair trick), +bt per col, pair out
    gemm_nt_p4<2, 2, true><<<dim3(N_ / 256, CI_ / 256, CHB), 512, 0, stream>>>(
        xT2, xt2B, 2 * C_, (const u16*)Wt2, 0L, 2 * C_, th2, th2B, 2 * CI_, bt, 2 * C_);

    // 3) ph2 likewise
    gemm_nt_p4<2, 2, true><<<dim3(N_ / 256, CI_ / 256, CHB), 512, 0, stream>>>(
        xT2, xt2B, 2 * C_, (const u16*)Wp2, 0L, 2 * C_, ph2, th2B, 2 * CI_, bp, 2 * C_);

    // 4) g[o][n] = Wg2 . xT2 (pair trick), +bg per row, bf16 out
    gemm_nt_p4<1, 0, true><<<dim3(CI_ / 256, N_ / 256, CHB), 512, 0, stream>>>(
        (const u16*)Wg2, 0L, 2 * C_, xT2, xt2B, 2 * C_, g, gB, N_, bg, 2 * C_);

    // 5) f[n][m] = th2 . ph2 (pair trick), fp32 out  (128^2: keeps 512 blocks)
    gemm_nt<0, 1, true><<<dim3(N_ / 128, N_ / 128, CHB), 256, 0, stream>>>(
        th2, th2B, 2 * CI_, ph2, th2B, 2 * CI_, f, fB, N_, nullptr, 2 * CI_);

    // 6) softmax rows -> bf16 attn in place
    softmax_k<<<dim3(CHB * N_), 256, 0, stream>>>(f);

    // 7) yT[n][ci] = attn . g
    gemm_nt_p4<0, 0, false><<<dim3(N_ / 256, CI_ / 256, CHB), 512, 0, stream>>>(
        (const u16*)f, attnB, 1024, g, gB, N_, yT, yB, CI_, nullptr, N_);

    // 8) wy[o][n] = Wob . yT + bo
    gemm_nt_p4<1, 0, false><<<dim3(C_ / 256, N_ / 256, CHB), 512, 0, stream>>>(
        Wob, 0L, CI_, yT, yB, CI_, wy + (long)h * CHB * wyB, wyB, N_, bo, CI_);
  }

  // 9) BN stats per channel (over all B)
  bn_stats_k<<<dim3(C_), 256, 0, stream>>>(wy, stats);

  // 10) BN apply + residual -> fp32 out (overwrites all d_out scratch)
  bn_apply_k<<<dim3((int)(((long)B_ * C_ * N_) / (256 * 8))), 256, 0, stream>>>(
      wy, x, stats, gamma, beta, out);
}

// Round 2
// 2293.314 us; speedup vs baseline: 1.1708x; 1.0137x over previous
//
#include <hip/hip_runtime.h>
#include <stdint.h>

typedef uint16_t u16;
typedef uint32_t u32;
typedef __attribute__((ext_vector_type(8))) short short8;
typedef __attribute__((ext_vector_type(4))) float f32x4;

// ---------- constants ----------
constexpr int B_  = 64;
constexpr int C_  = 2048;
constexpr int CI_ = 1024;
constexpr int N_  = 512;     // H*W
constexpr int CHB = 32;      // batches per chunk (2 chunks)

// ---------- bf16 helpers ----------
__device__ __forceinline__ float bf2f(u16 h){
  union{u32 u; float f;} v; v.u = ((u32)h) << 16; return v.f;
}
__device__ __forceinline__ u16 f2bf(float x){
  union{float f; u32 u;} v; v.f = x;
  u32 u = v.u;
  u32 r = u + 0x7fffu + ((u >> 16) & 1u);
  return (u16)(r >> 16);
}
__device__ __forceinline__ u32 split2(float v){
  u16 hi = f2bf(v);
  u16 lo = f2bf(v - bf2f(hi));
  return (u32)hi | ((u32)lo << 16);
}

// ---------- async global->LDS (16B per lane) ----------
__device__ __forceinline__ void gld_lds16(const void* gsrc, void* ldst){
  __builtin_amdgcn_global_load_lds(
      (__attribute__((address_space(1))) void*)(const_cast<void*>(gsrc)),
      (__attribute__((address_space(3))) void*)(ldst), 16, 0, 0);
}

// =====================================================================
// Pipelined NT GEMM: Out[m][n] = sum_k A[m][k]*B[n][k]  (+bias)
// TMxTN tile, BK=32, 512 threads (8 waves 2x4), per-wave (TM/2)x(TN/4).
// 4 LDS slots, stage prefetch distance 3, counted vmcnt (T3/T4), LDS
// chunk XOR swizzle on staging source + ds_read (T2), setprio (T5).
// NEW (round 2): A-fragment REGISTER double-buffer -- during iter t's
// MFMA cluster (operands loaded at iter t-1) we issue the ds_reads for
// tile t+1, hiding the 1152cy/CU LDS phase under the 2483cy MFMA phase.
// Legality: vmcnt keeps only 2 stages in flight => slot t+1 is staged
// before iter t's start barrier; slot t+1 is rewritten only at iter
// t+2's STAGE, which is behind iter t+1's end barrier.
// =====================================================================
template<int TM, int TN, int BIAS_MODE, int OUT_MODE, bool BSPLIT>
__global__ __launch_bounds__(512, 2)
void gemm_nt_p4(const u16* __restrict__ A, long aBatch, int lda,
                const u16* __restrict__ Bm, long bBatch, int ldb,
                void* __restrict__ Out, long oBatch, int ldo,
                const float* __restrict__ bias, int K)
{
  constexpr int BK   = 32;
  constexpr int WM   = TM / 2;
  constexpr int WN   = TN / 4;
  constexpr int AFR  = WM / 16;
  constexpr int BFR  = WN / 16;
  constexpr int SLOT = (TM + TN) * BK;       // u16 per slot
  constexpr int SOPS = (TM + TN) / 128;      // gld_lds ops per STAGE
  __shared__ __align__(16) u16 sm[4 * SLOT];

  const int bz = blockIdx.z;
  const int tm = blockIdx.x * TM;
  const int tn = blockIdx.y * TN;
  const u16* Ab = A  + (long)bz * aBatch;
  const u16* Bb = Bm + (long)bz * bBatch;

  const int tid  = threadIdx.x;
  const int wave = tid >> 6;
  const int lane = tid & 63;
  const int wr   = wave >> 2;               // 0..1  (M half)
  const int wc   = wave & 3;                // 0..3  (N quarter)
  const int lrow = lane & 15;
  const int quad = lane >> 4;

  const int NT = K / BK;

  f32x4 acc[AFR][BFR];
#pragma unroll
  for (int i = 0; i < AFR; ++i)
#pragma unroll
    for (int j = 0; j < BFR; ++j) acc[i][j] = f32x4{0.f, 0.f, 0.f, 0.f};

  short8 afA[AFR], afB[AFR], bfr[BFR];

#define STAGE(kt) do{ \
    u16* sl = &sm[((kt) & 3) * SLOT]; \
    const long kof = (long)(kt) * BK; \
    _Pragma("unroll") \
    for (int r = 0; r < TM / 128; ++r){ \
      const int c   = tid + 512 * r; \
      const int row = c >> 2; \
      const int sc  = ((c & 3) ^ ((row >> 1) & 3)) << 3; \
      gld_lds16(Ab + (long)(tm + row) * lda + kof + sc, sl + c * 8); \
    } \
    _Pragma("unroll") \
    for (int r = 0; r < TN / 128; ++r){ \
      const int c   = tid + 512 * r; \
      const int row = c >> 2; \
      const int sc  = ((c & 3) ^ ((row >> 1) & 3)) << 3; \
      gld_lds16(Bb + (long)(tn + row) * ldb + kof + sc, sl + TM * BK + c * 8); \
    } \
  }while(0)

#define LOADAF(tt, DST) do{ \
    const u16* Asl = &sm[((tt) & 3) * SLOT]; \
    _Pragma("unroll") \
    for (int i = 0; i < AFR; ++i){ \
      const int r8 = i * 16 + lrow; \
      DST[i] = *(const short8*)&Asl[(wr * WM + r8) * BK + ((quad ^ ((r8 >> 1) & 3)) << 3)]; \
    } \
  }while(0)

#define LOADBF(tt) do{ \
    const u16* Bsl = &sm[((tt) & 3) * SLOT + TM * BK]; \
    _Pragma("unroll") \
    for (int j = 0; j < BFR; ++j){ \
      const int n8 = j * 16 + lrow; \
      bfr[j] = *(const short8*)&Bsl[(wc * WN + n8) * BK + ((quad ^ ((n8 >> 1) & 3)) << 3)]; \
    } \
  }while(0)

#define MFMA_CL(AF) do{ \
    __builtin_amdgcn_s_setprio(1); \
    _Pragma("unroll") \
    for (int j = 0; j < BFR; ++j){ \
      const short8 b0 = bfr[j]; \
      const short8 b1 = __builtin_shufflevector(b0, b0, 1, 0, 3, 2, 5, 4, 7, 6); \
      _Pragma("unroll") \
      for (int i = 0; i < AFR; ++i){ \
        acc[i][j] = __builtin_amdgcn_mfma_f32_16x16x32_bf16(AF[i], b0, acc[i][j], 0, 0, 0); \
        if (BSPLIT) \
          acc[i][j] = __builtin_amdgcn_mfma_f32_16x16x32_bf16(AF[i], b1, acc[i][j], 0, 0, 0); \
      } \
    } \
    __builtin_amdgcn_s_setprio(0); \
  }while(0)

#define BAR() do{ asm volatile("" ::: "memory"); __builtin_amdgcn_s_barrier(); \
                  asm volatile("" ::: "memory"); }while(0)
// VMW2: keep 2 stages in flight; VMW1: keep 1; VMW0: drain.
#define VMW2() do{ if constexpr (SOPS == 4) asm volatile("s_waitcnt vmcnt(8)" ::: "memory"); \
                   else                      asm volatile("s_waitcnt vmcnt(6)" ::: "memory"); }while(0)
#define VMW1() do{ if constexpr (SOPS == 4) asm volatile("s_waitcnt vmcnt(4)" ::: "memory"); \
                   else                      asm volatile("s_waitcnt vmcnt(3)" ::: "memory"); }while(0)
#define VMW0() asm volatile("s_waitcnt vmcnt(0)" ::: "memory")

  STAGE(0); STAGE(1); STAGE(2);
  VMW2(); BAR();
  LOADAF(0, afA);

  int t = 0;
  for (; t + 4 < NT; t += 2){
    STAGE(t + 3); VMW2(); BAR(); LOADBF(t);     LOADAF(t + 1, afB); MFMA_CL(afA); BAR();
    STAGE(t + 4); VMW2(); BAR(); LOADBF(t + 1); LOADAF(t + 2, afA); MFMA_CL(afB); BAR();
  }
  // t == NT-4 here (NT always even, >= 16)
  STAGE(NT - 1); VMW2(); BAR(); LOADBF(NT - 4); LOADAF(NT - 3, afB); MFMA_CL(afA); BAR();
  VMW1();        BAR(); LOADBF(NT - 3); LOADAF(NT - 2, afA); MFMA_CL(afB); BAR();
  VMW0();        BAR(); LOADBF(NT - 2); LOADAF(NT - 1, afB); MFMA_CL(afA); BAR();
  LOADBF(NT - 1); MFMA_CL(afB);

#undef STAGE
#undef LOADAF
#undef LOADBF
#undef MFMA_CL
#undef BAR
#undef VMW2
#undef VMW1
#undef VMW0

  // epilogue: D[row][col], col=lane&15, row=quad*4+r (verified m89/m91)
  const long obase = (long)bz * oBatch;
#pragma unroll
  for (int i = 0; i < AFR; ++i){
    const int rbase = tm + wr * WM + i * 16 + quad * 4;
#pragma unroll
    for (int j = 0; j < BFR; ++j){
      const int col = tn + wc * WN + j * 16 + lrow;
      float cb = 0.f;
      if (BIAS_MODE == 2) cb = bias[col];
#pragma unroll
      for (int r = 0; r < 4; ++r){
        const int row = rbase + r;
        float v = acc[i][j][r];
        if (BIAS_MODE == 1) v += bias[row];
        if (BIAS_MODE == 2) v += cb;
        if (OUT_MODE == 1){
          ((float*)Out)[obase + (long)row * ldo + col] = v;
        } else if (OUT_MODE == 0){
          ((u16*)Out)[obase + (long)row * ldo + col] = f2bf(v);
        } else {
          *(u32*)((u16*)Out + obase + (long)row * ldo + col * 2) = split2(v);
        }
      }
    }
  }
}

// =====================================================================
// Transpose+split chunk: x [CHB,C,N] fp32 -> xT2 [CHB,N,2C] bf16 hi/lo
// =====================================================================
__global__ __launch_bounds__(1024)
void transpose_split_k(const float* __restrict__ x, u32* __restrict__ xT2)
{
  __shared__ float t[32][33];
  const int b  = blockIdx.z;
  const int n0 = blockIdx.x << 5;
  const int c0 = blockIdx.y << 5;
  const float* xb = x + (long)b * ((long)C_ * N_);
  u32* xo = xT2 + (long)b * ((long)N_ * C_);
  t[threadIdx.y][threadIdx.x] = xb[(long)(c0 + threadIdx.y) * N_ + n0 + threadIdx.x];
  __syncthreads();
  xo[(long)(n0 + threadIdx.y) * C_ + c0 + threadIdx.x] = split2(t[threadIdx.x][threadIdx.y]);
}

// =====================================================================
// Weight split: W fp32 [n] -> W2 u32 (bf16 hi|lo)
// =====================================================================
__global__ __launch_bounds__(256)
void wsplit_k(const float* __restrict__ W, u32* __restrict__ W2)
{
  const long i = ((long)blockIdx.x * 256 + threadIdx.x) * 4;
  const float4 v = *(const float4*)(W + i);
  uint4 o;
  o.x = split2(v.x); o.y = split2(v.y); o.z = split2(v.z); o.w = split2(v.w);
  *(uint4*)(W2 + i) = o;
}

// =====================================================================
// Plain fp32 -> bf16 pack (for Wo)
// =====================================================================
__global__ __launch_bounds__(256)
void pack_bf16_k(const float* __restrict__ W, u16* __restrict__ Wb)
{
  const long i = ((long)blockIdx.x * 256 + threadIdx.x) * 8;
  const float4 a = *(const float4*)(W + i);
  const float4 b = *(const float4*)(W + i + 4);
  uint4 o;
  o.x = (u32)f2bf(a.x) | ((u32)f2bf(a.y) << 16);
  o.y = (u32)f2bf(a.z) | ((u32)f2bf(a.w) << 16);
  o.z = (u32)f2bf(b.x) | ((u32)f2bf(b.y) << 16);
  o.w = (u32)f2bf(b.z) | ((u32)f2bf(b.w) << 16);
  *(uint4*)(Wb + i) = o;
}

// =====================================================================
// Row softmax over f [rows, 512] fp32; writes bf16 attn IN PLACE at row
// start (row stride stays 512 floats = 1024 u16).
// =====================================================================
__global__ __launch_bounds__(256)
void softmax_k(float* __restrict__ f)
{
  const long row = blockIdx.x;
  float* fr = f + (row << 9);
  const int tid = threadIdx.x;
  const float v0 = fr[tid];
  const float v1 = fr[tid + 256];

  float m = fmaxf(v0, v1);
#pragma unroll
  for (int off = 32; off; off >>= 1) m = fmaxf(m, __shfl_xor(m, off, 64));
  __shared__ float red[8];
  const int wave = tid >> 6, lane = tid & 63;
  if (!lane) red[wave] = m;
  __syncthreads();
  m = fmaxf(fmaxf(red[0], red[1]), fmaxf(red[2], red[3]));

  const float e0 = __expf(v0 - m);
  const float e1 = __expf(v1 - m);
  float s = e0 + e1;
#pragma unroll
  for (int off = 32; off; off >>= 1) s += __shfl_xor(s, off, 64);
  if (!lane) red[4 + wave] = s;
  __syncthreads();
  const float rs = 1.f / (red[4] + red[5] + red[6] + red[7]);

  u16* ar = (u16*)fr;
  ar[tid]       = f2bf(e0 * rs);
  ar[tid + 256] = f2bf(e1 * rs);
}

// =====================================================================
// BN stats per channel over (b,n): mean | rstd  (wy bf16 [B,C,N])
// =====================================================================
__global__ __launch_bounds__(256)
void bn_stats_k(const u16* __restrict__ wy, float* __restrict__ stats)
{
  const int c = blockIdx.x;
  const int tid = threadIdx.x;
  float s = 0.f, q = 0.f;
  const u16* base = wy + (long)c * N_;
  for (int b = 0; b < B_; ++b){
    const u32 w = ((const u32*)(base + (long)b * ((long)C_ * N_)))[tid];
    const float a0 = bf2f((u16)(w & 0xffff));
    const float a1 = bf2f((u16)(w >> 16));
    s += a0 + a1;
    q += a0 * a0 + a1 * a1;
  }
#pragma unroll
  for (int off = 32; off; off >>= 1){ s += __shfl_xor(s, off, 64); q += __shfl_xor(q, off, 64); }
  __shared__ float rs_[4], rq_[4];
  const int wave = tid >> 6, lane = tid & 63;
  if (!lane){ rs_[wave] = s; rq_[wave] = q; }
  __syncthreads();
  if (tid == 0){
    const float S = rs_[0] + rs_[1] + rs_[2] + rs_[3];
    const float Q = rq_[0] + rq_[1] + rq_[2] + rq_[3];
    const float inv = 1.f / (float)(B_ * N_);
    const float mean = S * inv;
    const float var  = Q * inv - mean * mean;
    stats[c]      = mean;
    stats[C_ + c] = rsqrtf(var + 1e-5f);
  }
}

// =====================================================================
// BN apply + residual: out = (wy-mean)*rstd*gamma + beta + x  (fp32 out)
// =====================================================================
__global__ __launch_bounds__(256)
void bn_apply_k(const u16* __restrict__ wy, const float* __restrict__ x,
                const float* __restrict__ stats,
                const float* __restrict__ gamma, const float* __restrict__ beta,
                float* __restrict__ out)
{
  const long i = ((long)blockIdx.x * 256 + threadIdx.x) * 8;
  const int c = (int)((i >> 9) & (C_ - 1));
  const float a  = stats[C_ + c] * gamma[c];
  const float b0 = beta[c] - stats[c] * a;

  const uint4 wv = *(const uint4*)(wy + i);
  const float4 x0 = *(const float4*)(x + i);
  const float4 x1 = *(const float4*)(x + i + 4);
  float4 o0, o1;
  o0.x = bf2f((u16)(wv.x & 0xffff)) * a + b0 + x0.x;
  o0.y = bf2f((u16)(wv.x >> 16))    * a + b0 + x0.y;
  o0.z = bf2f((u16)(wv.y & 0xffff)) * a + b0 + x0.z;
  o0.w = bf2f((u16)(wv.y >> 16))    * a + b0 + x0.w;
  o1.x = bf2f((u16)(wv.z & 0xffff)) * a + b0 + x1.x;
  o1.y = bf2f((u16)(wv.z >> 16))    * a + b0 + x1.y;
  o1.z = bf2f((u16)(wv.w & 0xffff)) * a + b0 + x1.z;
  o1.w = bf2f((u16)(wv.w >> 16))    * a + b0 + x1.w;
  *(float4*)(out + i)     = o0;
  *(float4*)(out + i + 4) = o1;
}

// =====================================================================
extern "C" void kernel_launch(void* const* d_in, const int* in_sizes, int n_in,
                              void* d_out, int out_size, void* d_ws, size_t ws_size,
                              hipStream_t stream)
{
  (void)in_sizes; (void)n_in; (void)out_size; (void)ws_size;
  const float* x     = (const float*)d_in[0];
  const float* Wg    = (const float*)d_in[1];
  const float* bg    = (const float*)d_in[2];
  const float* Wt    = (const float*)d_in[3];
  const float* bt    = (const float*)d_in[4];
  const float* Wp    = (const float*)d_in[5];
  const float* bp    = (const float*)d_in[6];
  const float* Wo    = (const float*)d_in[7];
  const float* bo    = (const float*)d_in[8];
  const float* gamma = (const float*)d_in[9];
  const float* beta  = (const float*)d_in[10];
  float* out = (float*)d_out;

  // ---- scratch in d_out (fully rewritten by bn_apply at the end) ----
  char* ob = (char*)d_out;
  u16* xT2 = (u16*)ob;
  u16* th2 = (u16*)(ob + 134217728L);
  u16* ph2 = (u16*)(ob + 134217728L + 67108864L);

  // ---- d_ws layout (~252 MiB) ----
  char* ws = (char*)d_ws;
  u16*   wy  = (u16*)ws;                         // [B,C,N] bf16  128 MiB
  u16*   g   = (u16*)(ws + 134217728L);          // chunk [CHB,Ci,N] 32 MiB
  float* f   = (float*)(ws + 134217728L + 33554432L);          // chunk 32 MiB
  u16*   yT  = (u16*)(ws + 134217728L + 2*33554432L);          // chunk 32 MiB
  u32*   Wg2 = (u32*)(ws + 134217728L + 3*33554432L);          // 8 MiB
  u32*   Wt2 = Wg2 + 2097152L;                                  // 8 MiB
  u32*   Wp2 = Wt2 + 2097152L;                                  // 8 MiB
  u16*   Wob = (u16*)(Wp2 + 2097152L);                          // 4 MiB
  float* stats = (float*)(Wob + 2097152L);                      // 16 KiB

  // ---- weight conversions (once per launch) ----
  wsplit_k<<<dim3(2097152 / (256 * 4)), 256, 0, stream>>>(Wg, Wg2);
  wsplit_k<<<dim3(2097152 / (256 * 4)), 256, 0, stream>>>(Wt, Wt2);
  wsplit_k<<<dim3(2097152 / (256 * 4)), 256, 0, stream>>>(Wp, Wp2);
  pack_bf16_k<<<dim3(2097152 / (256 * 8)), 256, 0, stream>>>(Wo, Wob);

  const long xBatch   = (long)C_ * N_;      // fp32 elems per batch of x
  const long xt2B     = (long)N_ * 2 * C_;  // u16 per batch
  const long th2B     = (long)N_ * 2 * CI_;
  const long gB       = (long)CI_ * N_;
  const long fB       = (long)N_ * N_;      // fp32
  const long attnB    = (long)N_ * 1024;    // u16 (row stride 1024)
  const long yB       = (long)N_ * CI_;
  const long wyB      = (long)C_ * N_;

  for (int h = 0; h < 2; ++h){
    const float* xc = x + (long)h * CHB * xBatch;

    // 1) transpose + hi/lo split
    transpose_split_k<<<dim3(N_ / 32, C_ / 32, CHB), dim3(32, 32), 0, stream>>>(
        xc, (u32*)xT2);

    // 2) th2[n][2o] = xT2 . Wt2 (pair trick), +bt per col, pair out
    gemm_nt_p4<256, 256, 2, 2, true><<<dim3(N_ / 256, CI_ / 256, CHB), 512, 0, stream>>>(
        xT2, xt2B, 2 * C_, (const u16*)Wt2, 0L, 2 * C_, th2, th2B, 2 * CI_, bt, 2 * C_);

    // 3) ph2 likewise
    gemm_nt_p4<256, 256, 2, 2, true><<<dim3(N_ / 256, CI_ / 256, CHB), 512, 0, stream>>>(
        xT2, xt2B, 2 * C_, (const u16*)Wp2, 0L, 2 * C_, ph2, th2B, 2 * CI_, bp, 2 * C_);

    // 4) g[o][n] = Wg2 . xT2 (pair trick), +bg per row, bf16 out
    gemm_nt_p4<256, 256, 1, 0, true><<<dim3(CI_ / 256, N_ / 256, CHB), 512, 0, stream>>>(
        (const u16*)Wg2, 0L, 2 * C_, xT2, xt2B, 2 * C_, g, gB, N_, bg, 2 * C_);

    // 5) f[n][m] = th2 . ph2 (pair trick), fp32 out
    //    128x256 tile: grid 4x2x32 = 256 blocks (256^2 would idle half the CUs)
    gemm_nt_p4<128, 256, 0, 1, true><<<dim3(N_ / 128, N_ / 256, CHB), 512, 0, stream>>>(
        th2, th2B, 2 * CI_, ph2, th2B, 2 * CI_, f, fB, N_, nullptr, 2 * CI_);

    // 6) softmax rows -> bf16 attn in place
    softmax_k<<<dim3(CHB * N_), 256, 0, stream>>>(f);

    // 7) yT[n][ci] = attn . g
    gemm_nt_p4<256, 256, 0, 0, false><<<dim3(N_ / 256, CI_ / 256, CHB), 512, 0, stream>>>(
        (const u16*)f, attnB, 1024, g, gB, N_, yT, yB, CI_, nullptr, N_);

    // 8) wy[o][n] = Wob . yT + bo
    gemm_nt_p4<256, 256, 1, 0, false><<<dim3(C_ / 256, N_ / 256, CHB), 512, 0, stream>>>(
        Wob, 0L, CI_, yT, yB, CI_, wy + (long)h * CHB * wyB, wyB, N_, bo, CI_);
  }

  // 9) BN stats per channel (over all B)
  bn_stats_k<<<dim3(C_), 256, 0, stream>>>(wy, stats);

  // 10) BN apply + residual -> fp32 out (overwrites all d_out scratch)
  bn_apply_k<<<dim3((int)(((long)B_ * C_ * N_) / (256 * 8))), 256, 0, stream>>>(
      wy, x, stats, gamma, beta, out);
}

// Round 3
// 2135.166 us; speedup vs baseline: 1.2575x; 1.0741x over previous
//
#include <hip/hip_runtime.h>
#include <stdint.h>

typedef uint16_t u16;
typedef uint32_t u32;
typedef __attribute__((ext_vector_type(8))) short short8;
typedef __attribute__((ext_vector_type(4))) float f32x4;

// ---------- constants ----------
constexpr int B_  = 64;
constexpr int C_  = 2048;
constexpr int CI_ = 1024;
constexpr int N_  = 512;     // H*W
constexpr int CHB = 32;      // batches per chunk (2 chunks)

// ---------- bf16 helpers ----------
__device__ __forceinline__ float bf2f(u16 h){
  union{u32 u; float f;} v; v.u = ((u32)h) << 16; return v.f;
}
__device__ __forceinline__ u16 f2bf(float x){
  union{float f; u32 u;} v; v.f = x;
  u32 u = v.u;
  u32 r = u + 0x7fffu + ((u >> 16) & 1u);
  return (u16)(r >> 16);
}
__device__ __forceinline__ u32 split2(float v){
  u16 hi = f2bf(v);
  u16 lo = f2bf(v - bf2f(hi));
  return (u32)hi | ((u32)lo << 16);
}

// ---------- async global->LDS (16B per lane) ----------
__device__ __forceinline__ void gld_lds16(const void* gsrc, void* ldst){
  __builtin_amdgcn_global_load_lds(
      (__attribute__((address_space(1))) void*)(const_cast<void*>(gsrc)),
      (__attribute__((address_space(3))) void*)(ldst), 16, 0, 0);
}

// =====================================================================
// Pipelined NT GEMM: Out[m][n] = sum_k A[m][k]*B[n][k]  (+bias)
// TMxTN tile, BK=32, 512 threads (8 waves 2x4), per-wave (TM/2)x(TN/4).
// 4 LDS slots, stage prefetch distance 3, counted vmcnt (T3/T4), LDS
// chunk XOR swizzle on staging source + ds_read (T2), setprio (T5).
// Round-3 schedule: the MFMA cluster for tile t depends on NO reads
// issued at its own phase head -- B fragments are read one-at-a-time
// INSIDE the cluster (each hides under the previous j-group's 16
// MFMAs), and the A-fragment prefetch for tile t+1 is issued AFTER the
// cluster (hidden under the co-wave's still-running MFMAs via pipe
// stagger). Round-2 evidence: phase = MFMA(2483cy) + LDS(1152cy) fully
// serialized because every wave's cluster waited on its LAST queued
// read (~1100cy) regardless of buffer identity.
// MODE: XCD-aware block remap (T1). 0 = share-A (y-fastest),
// 1 = share-B (x-fastest), 2 = batch-chunk (xy-fastest). All grids are
// multiples of 8 blocks; remap is bijective.
// =====================================================================
template<int TM, int TN, int MODE, int BIAS_MODE, int OUT_MODE, bool BSPLIT>
__global__ __launch_bounds__(512, 2)
void gemm_nt_p4(const u16* __restrict__ A, long aBatch, int lda,
                const u16* __restrict__ Bm, long bBatch, int ldb,
                void* __restrict__ Out, long oBatch, int ldo,
                const float* __restrict__ bias, int K)
{
  constexpr int BK   = 32;
  constexpr int WM   = TM / 2;
  constexpr int WN   = TN / 4;
  constexpr int AFR  = WM / 16;
  constexpr int BFR  = WN / 16;
  constexpr int SLOT = (TM + TN) * BK;       // u16 per slot
  constexpr int SOPS = (TM + TN) / 128;      // gld_lds ops per STAGE
  __shared__ __align__(16) u16 sm[4 * SLOT];

  // ---- XCD-aware bijective block remap ----
  const int gx = gridDim.x, gy = gridDim.y, gz = gridDim.z;
  const int nwg = gx * gy * gz;
  const int lid = blockIdx.x + gx * (blockIdx.y + gy * blockIdx.z);
  const int w   = (lid & 7) * (nwg >> 3) + (lid >> 3);
  int bx, by, bz;
  if (MODE == 0){       // share-A: co-XCD blocks span all y for fixed (x, z-range)
    by = w % gy; const int r = w / gy; bz = r % gz; bx = r / gz;
  } else if (MODE == 1){ // share-B: co-XCD blocks span all x for fixed (y, z-range)
    bx = w % gx; const int r = w / gx; bz = r % gz; by = r / gz;
  } else {              // batch-chunk: co-XCD blocks = whole batches
    const int xy = w % (gx * gy); bx = xy % gx; by = xy / gx; bz = w / (gx * gy);
  }

  const int tm = bx * TM;
  const int tn = by * TN;
  const u16* Ab = A  + (long)bz * aBatch;
  const u16* Bb = Bm + (long)bz * bBatch;

  const int tid  = threadIdx.x;
  const int wave = tid >> 6;
  const int lane = tid & 63;
  const int wr   = wave >> 2;               // 0..1  (M half)
  const int wc   = wave & 3;                // 0..3  (N quarter)
  const int lrow = lane & 15;
  const int quad = lane >> 4;

  const int NT = K / BK;

  f32x4 acc[AFR][BFR];
#pragma unroll
  for (int i = 0; i < AFR; ++i)
#pragma unroll
    for (int j = 0; j < BFR; ++j) acc[i][j] = f32x4{0.f, 0.f, 0.f, 0.f};

  short8 afA[AFR], afB[AFR];

#define STAGE(kt) do{ \
    u16* sl = &sm[((kt) & 3) * SLOT]; \
    const long kof = (long)(kt) * BK; \
    _Pragma("unroll") \
    for (int r = 0; r < TM / 128; ++r){ \
      const int c   = tid + 512 * r; \
      const int row = c >> 2; \
      const int sc  = ((c & 3) ^ ((row >> 1) & 3)) << 3; \
      gld_lds16(Ab + (long)(tm + row) * lda + kof + sc, sl + c * 8); \
    } \
    _Pragma("unroll") \
    for (int r = 0; r < TN / 128; ++r){ \
      const int c   = tid + 512 * r; \
      const int row = c >> 2; \
      const int sc  = ((c & 3) ^ ((row >> 1) & 3)) << 3; \
      gld_lds16(Bb + (long)(tn + row) * ldb + kof + sc, sl + TM * BK + c * 8); \
    } \
  }while(0)

#define LOADAF(tt, DST) do{ \
    const u16* Asl = &sm[((tt) & 3) * SLOT]; \
    _Pragma("unroll") \
    for (int i = 0; i < AFR; ++i){ \
      const int r8 = i * 16 + lrow; \
      DST[i] = *(const short8*)&Asl[(wr * WM + r8) * BK + ((quad ^ ((r8 >> 1) & 3)) << 3)]; \
    } \
  }while(0)

// MFMA cluster for tile tt: B fragments read inline (one per j-group,
// rotating register), so the first MFMA waits only on bfr_0.
#define CLUST(tt, AF) do{ \
    const u16* Bsl = &sm[((tt) & 3) * SLOT + TM * BK]; \
    __builtin_amdgcn_s_setprio(1); \
    _Pragma("unroll") \
    for (int j = 0; j < BFR; ++j){ \
      const int n8 = j * 16 + lrow; \
      const short8 b0 = *(const short8*)&Bsl[(wc * WN + n8) * BK + ((quad ^ ((n8 >> 1) & 3)) << 3)]; \
      _Pragma("unroll") \
      for (int i = 0; i < AFR; ++i) \
        acc[i][j] = __builtin_amdgcn_mfma_f32_16x16x32_bf16(AF[i], b0, acc[i][j], 0, 0, 0); \
      if (BSPLIT){ \
        const short8 b1 = __builtin_shufflevector(b0, b0, 1, 0, 3, 2, 5, 4, 7, 6); \
        _Pragma("unroll") \
        for (int i = 0; i < AFR; ++i) \
          acc[i][j] = __builtin_amdgcn_mfma_f32_16x16x32_bf16(AF[i], b1, acc[i][j], 0, 0, 0); \
      } \
    } \
    __builtin_amdgcn_s_setprio(0); \
  }while(0)

#define BAR() do{ asm volatile("" ::: "memory"); __builtin_amdgcn_s_barrier(); \
                  asm volatile("" ::: "memory"); }while(0)
// VMW2: keep 2 stages in flight; VMW1: keep 1; VMW0: drain.
#define VMW2() do{ if constexpr (SOPS == 4) asm volatile("s_waitcnt vmcnt(8)" ::: "memory"); \
                   else                      asm volatile("s_waitcnt vmcnt(6)" ::: "memory"); }while(0)
#define VMW1() do{ if constexpr (SOPS == 4) asm volatile("s_waitcnt vmcnt(4)" ::: "memory"); \
                   else                      asm volatile("s_waitcnt vmcnt(3)" ::: "memory"); }while(0)
#define VMW0() asm volatile("s_waitcnt vmcnt(0)" ::: "memory")

  STAGE(0); STAGE(1); STAGE(2);
  VMW2(); BAR();
  LOADAF(0, afA);

  int t = 0;
  for (; t + 4 < NT; t += 2){
    STAGE(t + 3); VMW2(); BAR(); CLUST(t,     afA); LOADAF(t + 1, afB); BAR();
    STAGE(t + 4); VMW2(); BAR(); CLUST(t + 1, afB); LOADAF(t + 2, afA); BAR();
  }
  // t == NT-4 here (NT always even, >= 16)
  STAGE(NT - 1); VMW2(); BAR(); CLUST(NT - 4, afA); LOADAF(NT - 3, afB); BAR();
  VMW1(); BAR(); CLUST(NT - 3, afB); LOADAF(NT - 2, afA); BAR();
  VMW0(); BAR(); CLUST(NT - 2, afA); LOADAF(NT - 1, afB); BAR();
  CLUST(NT - 1, afB);

#undef STAGE
#undef LOADAF
#undef CLUST
#undef BAR
#undef VMW2
#undef VMW1
#undef VMW0

  // epilogue: D[row][col], col=lane&15, row=quad*4+r (verified m89/m91)
  const long obase = (long)bz * oBatch;
#pragma unroll
  for (int i = 0; i < AFR; ++i){
    const int rbase = tm + wr * WM + i * 16 + quad * 4;
#pragma unroll
    for (int j = 0; j < BFR; ++j){
      const int col = tn + wc * WN + j * 16 + lrow;
      float cb = 0.f;
      if (BIAS_MODE == 2) cb = bias[col];
#pragma unroll
      for (int r = 0; r < 4; ++r){
        const int row = rbase + r;
        float v = acc[i][j][r];
        if (BIAS_MODE == 1) v += bias[row];
        if (BIAS_MODE == 2) v += cb;
        if (OUT_MODE == 1){
          ((float*)Out)[obase + (long)row * ldo + col] = v;
        } else if (OUT_MODE == 0){
          ((u16*)Out)[obase + (long)row * ldo + col] = f2bf(v);
        } else {
          *(u32*)((u16*)Out + obase + (long)row * ldo + col * 2) = split2(v);
        }
      }
    }
  }
}

// =====================================================================
// Transpose+split chunk: x [CHB,C,N] fp32 -> xT2 [CHB,N,2C] bf16 hi/lo
// =====================================================================
__global__ __launch_bounds__(1024)
void transpose_split_k(const float* __restrict__ x, u32* __restrict__ xT2)
{
  __shared__ float t[32][33];
  const int b  = blockIdx.z;
  const int n0 = blockIdx.x << 5;
  const int c0 = blockIdx.y << 5;
  const float* xb = x + (long)b * ((long)C_ * N_);
  u32* xo = xT2 + (long)b * ((long)N_ * C_);
  t[threadIdx.y][threadIdx.x] = xb[(long)(c0 + threadIdx.y) * N_ + n0 + threadIdx.x];
  __syncthreads();
  xo[(long)(n0 + threadIdx.y) * C_ + c0 + threadIdx.x] = split2(t[threadIdx.x][threadIdx.y]);
}

// =====================================================================
// Weight split: W fp32 [n] -> W2 u32 (bf16 hi|lo)
// =====================================================================
__global__ __launch_bounds__(256)
void wsplit_k(const float* __restrict__ W, u32* __restrict__ W2)
{
  const long i = ((long)blockIdx.x * 256 + threadIdx.x) * 4;
  const float4 v = *(const float4*)(W + i);
  uint4 o;
  o.x = split2(v.x); o.y = split2(v.y); o.z = split2(v.z); o.w = split2(v.w);
  *(uint4*)(W2 + i) = o;
}

// =====================================================================
// Plain fp32 -> bf16 pack (for Wo)
// =====================================================================
__global__ __launch_bounds__(256)
void pack_bf16_k(const float* __restrict__ W, u16* __restrict__ Wb)
{
  const long i = ((long)blockIdx.x * 256 + threadIdx.x) * 8;
  const float4 a = *(const float4*)(W + i);
  const float4 b = *(const float4*)(W + i + 4);
  uint4 o;
  o.x = (u32)f2bf(a.x) | ((u32)f2bf(a.y) << 16);
  o.y = (u32)f2bf(a.z) | ((u32)f2bf(a.w) << 16);
  o.z = (u32)f2bf(b.x) | ((u32)f2bf(b.y) << 16);
  o.w = (u32)f2bf(b.z) | ((u32)f2bf(b.w) << 16);
  *(uint4*)(Wb + i) = o;
}

// =====================================================================
// Row softmax over f [rows, 512] fp32; writes bf16 attn IN PLACE at row
// start (row stride stays 512 floats = 1024 u16).
// =====================================================================
__global__ __launch_bounds__(256)
void softmax_k(float* __restrict__ f)
{
  const long row = blockIdx.x;
  float* fr = f + (row << 9);
  const int tid = threadIdx.x;
  const float v0 = fr[tid];
  const float v1 = fr[tid + 256];

  float m = fmaxf(v0, v1);
#pragma unroll
  for (int off = 32; off; off >>= 1) m = fmaxf(m, __shfl_xor(m, off, 64));
  __shared__ float red[8];
  const int wave = tid >> 6, lane = tid & 63;
  if (!lane) red[wave] = m;
  __syncthreads();
  m = fmaxf(fmaxf(red[0], red[1]), fmaxf(red[2], red[3]));

  const float e0 = __expf(v0 - m);
  const float e1 = __expf(v1 - m);
  float s = e0 + e1;
#pragma unroll
  for (int off = 32; off; off >>= 1) s += __shfl_xor(s, off, 64);
  if (!lane) red[4 + wave] = s;
  __syncthreads();
  const float rs = 1.f / (red[4] + red[5] + red[6] + red[7]);

  u16* ar = (u16*)fr;
  ar[tid]       = f2bf(e0 * rs);
  ar[tid + 256] = f2bf(e1 * rs);
}

// =====================================================================
// BN stats per channel over (b,n): mean | rstd  (wy bf16 [B,C,N])
// =====================================================================
__global__ __launch_bounds__(256)
void bn_stats_k(const u16* __restrict__ wy, float* __restrict__ stats)
{
  const int c = blockIdx.x;
  const int tid = threadIdx.x;
  float s = 0.f, q = 0.f;
  const u16* base = wy + (long)c * N_;
  for (int b = 0; b < B_; ++b){
    const u32 w = ((const u32*)(base + (long)b * ((long)C_ * N_)))[tid];
    const float a0 = bf2f((u16)(w & 0xffff));
    const float a1 = bf2f((u16)(w >> 16));
    s += a0 + a1;
    q += a0 * a0 + a1 * a1;
  }
#pragma unroll
  for (int off = 32; off; off >>= 1){ s += __shfl_xor(s, off, 64); q += __shfl_xor(q, off, 64); }
  __shared__ float rs_[4], rq_[4];
  const int wave = tid >> 6, lane = tid & 63;
  if (!lane){ rs_[wave] = s; rq_[wave] = q; }
  __syncthreads();
  if (tid == 0){
    const float S = rs_[0] + rs_[1] + rs_[2] + rs_[3];
    const float Q = rq_[0] + rq_[1] + rq_[2] + rq_[3];
    const float inv = 1.f / (float)(B_ * N_);
    const float mean = S * inv;
    const float var  = Q * inv - mean * mean;
    stats[c]      = mean;
    stats[C_ + c] = rsqrtf(var + 1e-5f);
  }
}

// =====================================================================
// BN apply + residual: out = (wy-mean)*rstd*gamma + beta + x  (fp32 out)
// =====================================================================
__global__ __launch_bounds__(256)
void bn_apply_k(const u16* __restrict__ wy, const float* __restrict__ x,
                const float* __restrict__ stats,
                const float* __restrict__ gamma, const float* __restrict__ beta,
                float* __restrict__ out)
{
  const long i = ((long)blockIdx.x * 256 + threadIdx.x) * 8;
  const int c = (int)((i >> 9) & (C_ - 1));
  const float a  = stats[C_ + c] * gamma[c];
  const float b0 = beta[c] - stats[c] * a;

  const uint4 wv = *(const uint4*)(wy + i);
  const float4 x0 = *(const float4*)(x + i);
  const float4 x1 = *(const float4*)(x + i + 4);
  float4 o0, o1;
  o0.x = bf2f((u16)(wv.x & 0xffff)) * a + b0 + x0.x;
  o0.y = bf2f((u16)(wv.x >> 16))    * a + b0 + x0.y;
  o0.z = bf2f((u16)(wv.y & 0xffff)) * a + b0 + x0.z;
  o0.w = bf2f((u16)(wv.y >> 16))    * a + b0 + x0.w;
  o1.x = bf2f((u16)(wv.z & 0xffff)) * a + b0 + x1.x;
  o1.y = bf2f((u16)(wv.z >> 16))    * a + b0 + x1.y;
  o1.z = bf2f((u16)(wv.w & 0xffff)) * a + b0 + x1.z;
  o1.w = bf2f((u16)(wv.w >> 16))    * a + b0 + x1.w;
  *(float4*)(out + i)     = o0;
  *(float4*)(out + i + 4) = o1;
}

// =====================================================================
extern "C" void kernel_launch(void* const* d_in, const int* in_sizes, int n_in,
                              void* d_out, int out_size, void* d_ws, size_t ws_size,
                              hipStream_t stream)
{
  (void)in_sizes; (void)n_in; (void)out_size; (void)ws_size;
  const float* x     = (const float*)d_in[0];
  const float* Wg    = (const float*)d_in[1];
  const float* bg    = (const float*)d_in[2];
  const float* Wt    = (const float*)d_in[3];
  const float* bt    = (const float*)d_in[4];
  const float* Wp    = (const float*)d_in[5];
  const float* bp    = (const float*)d_in[6];
  const float* Wo    = (const float*)d_in[7];
  const float* bo    = (const float*)d_in[8];
  const float* gamma = (const float*)d_in[9];
  const float* beta  = (const float*)d_in[10];
  float* out = (float*)d_out;

  // ---- scratch in d_out (fully rewritten by bn_apply at the end) ----
  char* ob = (char*)d_out;
  u16* xT2 = (u16*)ob;
  u16* th2 = (u16*)(ob + 134217728L);
  u16* ph2 = (u16*)(ob + 134217728L + 67108864L);

  // ---- d_ws layout (~252 MiB) ----
  char* ws = (char*)d_ws;
  u16*   wy  = (u16*)ws;                         // [B,C,N] bf16  128 MiB
  u16*   g   = (u16*)(ws + 134217728L);          // chunk [CHB,Ci,N] 32 MiB
  float* f   = (float*)(ws + 134217728L + 33554432L);          // chunk 32 MiB
  u16*   yT  = (u16*)(ws + 134217728L + 2*33554432L);          // chunk 32 MiB
  u32*   Wg2 = (u32*)(ws + 134217728L + 3*33554432L);          // 8 MiB
  u32*   Wt2 = Wg2 + 2097152L;                                  // 8 MiB
  u32*   Wp2 = Wt2 + 2097152L;                                  // 8 MiB
  u16*   Wob = (u16*)(Wp2 + 2097152L);                          // 4 MiB
  float* stats = (float*)(Wob + 2097152L);                      // 16 KiB

  // ---- weight conversions (once per launch) ----
  wsplit_k<<<dim3(2097152 / (256 * 4)), 256, 0, stream>>>(Wg, Wg2);
  wsplit_k<<<dim3(2097152 / (256 * 4)), 256, 0, stream>>>(Wt, Wt2);
  wsplit_k<<<dim3(2097152 / (256 * 4)), 256, 0, stream>>>(Wp, Wp2);
  pack_bf16_k<<<dim3(2097152 / (256 * 8)), 256, 0, stream>>>(Wo, Wob);

  const long xBatch   = (long)C_ * N_;      // fp32 elems per batch of x
  const long xt2B     = (long)N_ * 2 * C_;  // u16 per batch
  const long th2B     = (long)N_ * 2 * CI_;
  const long gB       = (long)CI_ * N_;
  const long fB       = (long)N_ * N_;      // fp32
  const long attnB    = (long)N_ * 1024;    // u16 (row stride 1024)
  const long yB       = (long)N_ * CI_;
  const long wyB      = (long)C_ * N_;

  for (int h = 0; h < 2; ++h){
    const float* xc = x + (long)h * CHB * xBatch;

    // 1) transpose + hi/lo split
    transpose_split_k<<<dim3(N_ / 32, C_ / 32, CHB), dim3(32, 32), 0, stream>>>(
        xc, (u32*)xT2);

    // 2) th2[n][2o] = xT2 . Wt2 (pair trick), +bt per col, pair out
    //    MODE 0: A = xT2 (big, per-batch) shared across blockIdx.y
    gemm_nt_p4<256, 256, 0, 2, 2, true><<<dim3(N_ / 256, CI_ / 256, CHB), 512, 0, stream>>>(
        xT2, xt2B, 2 * C_, (const u16*)Wt2, 0L, 2 * C_, th2, th2B, 2 * CI_, bt, 2 * C_);

    // 3) ph2 likewise
    gemm_nt_p4<256, 256, 0, 2, 2, true><<<dim3(N_ / 256, CI_ / 256, CHB), 512, 0, stream>>>(
        xT2, xt2B, 2 * C_, (const u16*)Wp2, 0L, 2 * C_, ph2, th2B, 2 * CI_, bp, 2 * C_);

    // 4) g[o][n] = Wg2 . xT2 (pair trick), +bg per row, bf16 out
    //    MODE 1: B = xT2 (big) shared across blockIdx.x
    gemm_nt_p4<256, 256, 1, 1, 0, true><<<dim3(CI_ / 256, N_ / 256, CHB), 512, 0, stream>>>(
        (const u16*)Wg2, 0L, 2 * C_, xT2, xt2B, 2 * C_, g, gB, N_, bg, 2 * C_);

    // 5) f[n][m] = th2 . ph2 (pair trick), fp32 out
    //    128x256 tile keeps 256 blocks; MODE 2 batch-chunk
    gemm_nt_p4<128, 256, 2, 0, 1, true><<<dim3(N_ / 128, N_ / 256, CHB), 512, 0, stream>>>(
        th2, th2B, 2 * CI_, ph2, th2B, 2 * CI_, f, fB, N_, nullptr, 2 * CI_);

    // 6) softmax rows -> bf16 attn in place
    softmax_k<<<dim3(CHB * N_), 256, 0, stream>>>(f);

    // 7) yT[n][ci] = attn . g   MODE 2 batch-chunk
    gemm_nt_p4<256, 256, 2, 0, 0, false><<<dim3(N_ / 256, CI_ / 256, CHB), 512, 0, stream>>>(
        (const u16*)f, attnB, 1024, g, gB, N_, yT, yB, CI_, nullptr, N_);

    // 8) wy[o][n] = Wob . yT + bo   MODE 1: B = yT (big) shared across blockIdx.x
    gemm_nt_p4<256, 256, 1, 1, 0, false><<<dim3(C_ / 256, N_ / 256, CHB), 512, 0, stream>>>(
        Wob, 0L, CI_, yT, yB, CI_, wy + (long)h * CHB * wyB, wyB, N_, bo, CI_);
  }

  // 9) BN stats per channel (over all B)
  bn_stats_k<<<dim3(C_), 256, 0, stream>>>(wy, stats);

  // 10) BN apply + residual -> fp32 out (overwrites all d_out scratch)
  bn_apply_k<<<dim3((int)(((long)B_ * C_ * N_) / (256 * 8))), 256, 0, stream>>>(
      wy, x, stats, gamma, beta, out);
}